// Round 7
// baseline (793.596 us; speedup 1.0000x reference)
//
#include <hip/hip_runtime.h>

// out[e] = segment_sum(M, dest)[src[e]] - M[rev_index[e]]
// E = 800,000, D = 64 (fp32), N_NODES = 50,000.
//
// Round-7: owner-computes reduction. No CSR, no sorted copy, 2 kernels total.
//  K1 owner_reduce: 256 blocks x 1024 threads. Block b owns nodes
//    [196b, 196b+196) with a 50 KB LDS accumulator. Each block scans the FULL
//    dest[] in e-order (3.2 MB; L2-broadcast, ~102 MB/XCD ~ 24 us), ballots
//    matched edges, and per match the wave loads M[e] (coalesced 256 B) and
//    ds_add_f32's into LDS. Aggregate M traffic = e-ascending STREAM, each row
//    read once. Coalesced Mv writeback. Kills hist/alloc/bin/memset.
//  K2 agg_gather: unchanged r5 gather (2-edge ILP, nt out-stores).
// Measured rules honored: no fp32 global atomics (r3: 683 us), no hot-line
// cursor atomics (r4: 588 us), no fp16/LLC tricks (r6: null — random-row wall
// is not byte-BW and not HBM-vs-LLC), LDS f32 atomics are native & cheap (r4).

#define D 64
#define N_NODES 50000
#define NPB 196                       // nodes per block; 256*196 = 50176 >= 50000
#define RBLOCKS ((N_NODES + NPB - 1) / NPB)   // 256

typedef float f4 __attribute__((ext_vector_type(4)));

// K1: owner-computes segmented sum. One block per node-range, full edge scan.
__global__ __launch_bounds__(1024) void owner_reduce(const float* __restrict__ M,
                                                     const int* __restrict__ dest,
                                                     float* __restrict__ Mv, int E) {
    __shared__ float acc[NPB * D];    // 196*64*4 = 50176 B
    const int t    = threadIdx.x;
    const int lane = t & 63;
    const int wv   = t >> 6;          // 0..15
    const int lo   = blockIdx.x * NPB;
    const int hi   = (lo + NPB < N_NODES) ? lo + NPB : N_NODES;

    for (int i = t; i < NPB * D; i += 1024) acc[i] = 0.f;
    __syncthreads();

    const int nchunk = (E + 63) >> 6;
    for (int c = wv; c < nchunk; c += 16) {
        int e = (c << 6) + lane;
        int d = (e < E) ? dest[e] : -1;           // coalesced; L2-broadcast across blocks
        bool mine = (d >= lo) && (d < hi);
        unsigned long long mask = __ballot(mine);
        while (mask) {
            int sl = __ffsll(mask) - 1;
            mask &= mask - 1;
            int em = (c << 6) + sl;
            int dm = __shfl(d, sl, 64);
            float v = M[(size_t)em * D + lane];   // one coalesced 256 B row / wave
            atomicAdd(&acc[(dm - lo) * D + lane], v);  // native ds_add_f32; 2-way bank = free
        }
    }
    __syncthreads();

    const int nout = (hi - lo) * D;
    for (int i = t; i < nout; i += 1024)
        Mv[(size_t)lo * D + i] = acc[i];          // coalesced writeback
}

// K2: out[e] = Mv[src[e]] - M[rev[e]]. 2 edges per 16-lane group -> 4
// outstanding row loads per thread. nt stores: out is never re-read.
__global__ void agg_gather(const float* __restrict__ Mv,
                           const float* __restrict__ M,
                           const int* __restrict__ src,
                           const int* __restrict__ rev,
                           float* __restrict__ out,
                           int E) {
    int gid = blockIdx.x * blockDim.x + threadIdx.x;
    int p  = gid >> 4;
    int c4 = gid & 15;
    int e0 = p << 1;
    if (e0 >= E) return;
    int e1 = e0 + 1;
    int e1c = (e1 < E) ? e1 : e0;
    int s0 = src[e0], r0 = rev[e0];
    int s1 = src[e1c], r1 = rev[e1c];
    f4 a0 = reinterpret_cast<const f4*>(Mv + (size_t)s0 * D)[c4];
    f4 b0 = reinterpret_cast<const f4*>(M  + (size_t)r0 * D)[c4];
    f4 a1 = reinterpret_cast<const f4*>(Mv + (size_t)s1 * D)[c4];
    f4 b1 = reinterpret_cast<const f4*>(M  + (size_t)r1 * D)[c4];
    f4 o0 = a0 - b0;
    __builtin_nontemporal_store(o0, reinterpret_cast<f4*>(out + (size_t)e0 * D) + c4);
    if (e1 < E) {
        f4 o1 = a1 - b1;
        __builtin_nontemporal_store(o1, reinterpret_cast<f4*>(out + (size_t)e1 * D) + c4);
    }
}

extern "C" void kernel_launch(void* const* d_in, const int* in_sizes, int n_in,
                              void* d_out, int out_size, void* d_ws, size_t ws_size,
                              hipStream_t stream) {
    const float* M   = (const float*)d_in[0];
    const int*   ei  = (const int*)d_in[1];   // (2, E) row-major: [src | dest]
    const int*   rev = (const int*)d_in[2];

    int E = in_sizes[0] / D;                  // 800,000
    const int* src  = ei;
    const int* dest = ei + E;

    float* Mv = (float*)d_ws;                 // 12.8 MB — only workspace user

    owner_reduce<<<RBLOCKS, 1024, 0, stream>>>(M, dest, Mv, E);

    int gb = (int)(((size_t)((E + 1) / 2) * 16 + 255) / 256);
    agg_gather<<<gb, 256, 0, stream>>>(Mv, M, src, rev, (float*)d_out, E);
}

// Round 8
// 619.762 us; speedup vs baseline: 1.2805x; 1.2805x over previous
//
#include <hip/hip_runtime.h>

// out[e] = segment_sum(M, dest)[src[e]] - M[rev_index[e]]
// E = 800,000, D = 64 (fp32), N_NODES = 50,000.
//
// Round-8: owner-computes reduction with fixed memory-level parallelism.
// r7 post-mortem: owner_reduce was dependent-load latency-bound (HBM 3.3%,
// VALUBusy 15%, one dest load in flight per wave, ~1000cy x 781 iter). Fix:
// each wave-iteration loads 4 independent int4 vectors (4 loads in flight,
// 1024 edges/iteration) -> 49 iterations/wave, one amortized wait each.
//  K1 owner_reduce: 256 blocks x 1024 thr. Block b owns nodes [196b,196b+196)
//    in a 50 KB LDS accumulator; scans all of dest[] as int4 x4; ballots per
//    component; per match the wave loads M[e] (coalesced 256 B) + ds_add_f32.
//    Aggregate M traffic stays ~one streaming pass (r7: FETCH 112 MB).
//  K2 agg_gather: unchanged (2-edge ILP, nt out-stores) — measured ~60-90 us.
// Rules honored: no fp32 global atomics (r3), no hot-line atomics (r4), no
// fp16/LLC tricks (r6 null), LDS f32 atomics native & 2-way-bank-free.

#define D 64
#define N_NODES 50000
#define NPB 196                                // nodes per block
#define RBLOCKS ((N_NODES + NPB - 1) / NPB)    // 256

typedef float f4 __attribute__((ext_vector_type(4)));

__global__ __launch_bounds__(1024) void owner_reduce(const float* __restrict__ M,
                                                     const int* __restrict__ dest,
                                                     float* __restrict__ Mv, int E) {
    __shared__ float acc[NPB * D];             // 50,176 B
    const int t    = threadIdx.x;
    const int lane = t & 63;
    const int wv   = t >> 6;                   // 0..15
    const int lo   = blockIdx.x * NPB;
    const int hi   = (lo + NPB < N_NODES) ? lo + NPB : N_NODES;

    for (int i = t; i < NPB * D; i += 1024) acc[i] = 0.f;
    __syncthreads();

    const int4* d4 = reinterpret_cast<const int4*>(dest);
    const int n4 = E >> 2;                     // 200,000 int4s
    const int4 none = {-1, -1, -1, -1};

    // Wave wv handles int4-index blocks [base, base+256) each round;
    // block round stride = 16 waves * 256 = 4096 int4s.
    for (int base = wv * 256; base < n4; base += 16 * 256) {
        int i0 = base + lane;
        int i1 = base + 64  + lane;
        int i2 = base + 128 + lane;
        int i3 = base + 192 + lane;
        // 4 independent loads in flight (the r7 fix)
        int4 v0 = (i0 < n4) ? d4[i0] : none;
        int4 v1 = (i1 < n4) ? d4[i1] : none;
        int4 v2 = (i2 < n4) ? d4[i2] : none;
        int4 v3 = (i3 < n4) ? d4[i3] : none;

        #pragma unroll
        for (int g = 0; g < 4; ++g) {
            int4 v = (g == 0) ? v0 : (g == 1) ? v1 : (g == 2) ? v2 : v3;
            int gbase = base + (g << 6);       // int4-index base of this group
            #pragma unroll
            for (int k = 0; k < 4; ++k) {
                int dk = (k == 0) ? v.x : (k == 1) ? v.y : (k == 2) ? v.z : v.w;
                unsigned long long mask = __ballot(dk >= lo && dk < hi);
                while (mask) {
                    int sl = __ffsll(mask) - 1;
                    mask &= mask - 1;
                    int dm = __shfl(dk, sl, 64);
                    int em = ((gbase + sl) << 2) + k;
                    float val = M[(size_t)em * D + lane];   // coalesced 256 B row
                    atomicAdd(&acc[(dm - lo) * D + lane], val);  // ds_add_f32
                }
            }
        }
    }
    __syncthreads();

    const int nout = (hi - lo) * D;
    for (int i = t; i < nout; i += 1024)
        Mv[(size_t)lo * D + i] = acc[i];       // coalesced writeback
}

// K2: out[e] = Mv[src[e]] - M[rev[e]]. 2 edges per 16-lane group -> 4
// outstanding row loads per thread. nt stores: out is never re-read.
__global__ void agg_gather(const float* __restrict__ Mv,
                           const float* __restrict__ M,
                           const int* __restrict__ src,
                           const int* __restrict__ rev,
                           float* __restrict__ out,
                           int E) {
    int gid = blockIdx.x * blockDim.x + threadIdx.x;
    int p  = gid >> 4;
    int c4 = gid & 15;
    int e0 = p << 1;
    if (e0 >= E) return;
    int e1 = e0 + 1;
    int e1c = (e1 < E) ? e1 : e0;
    int s0 = src[e0], r0 = rev[e0];
    int s1 = src[e1c], r1 = rev[e1c];
    f4 a0 = reinterpret_cast<const f4*>(Mv + (size_t)s0 * D)[c4];
    f4 b0 = reinterpret_cast<const f4*>(M  + (size_t)r0 * D)[c4];
    f4 a1 = reinterpret_cast<const f4*>(Mv + (size_t)s1 * D)[c4];
    f4 b1 = reinterpret_cast<const f4*>(M  + (size_t)r1 * D)[c4];
    f4 o0 = a0 - b0;
    __builtin_nontemporal_store(o0, reinterpret_cast<f4*>(out + (size_t)e0 * D) + c4);
    if (e1 < E) {
        f4 o1 = a1 - b1;
        __builtin_nontemporal_store(o1, reinterpret_cast<f4*>(out + (size_t)e1 * D) + c4);
    }
}

extern "C" void kernel_launch(void* const* d_in, const int* in_sizes, int n_in,
                              void* d_out, int out_size, void* d_ws, size_t ws_size,
                              hipStream_t stream) {
    const float* M   = (const float*)d_in[0];
    const int*   ei  = (const int*)d_in[1];   // (2, E) row-major: [src | dest]
    const int*   rev = (const int*)d_in[2];

    int E = in_sizes[0] / D;                  // 800,000
    const int* src  = ei;
    const int* dest = ei + E;

    float* Mv = (float*)d_ws;                 // 12.8 MB — only workspace user

    owner_reduce<<<RBLOCKS, 1024, 0, stream>>>(M, dest, Mv, E);

    int gb = (int)(((size_t)((E + 1) / 2) * 16 + 255) / 256);
    agg_gather<<<gb, 256, 0, stream>>>(Mv, M, src, rev, (float*)d_out, E);
}

// Round 9
// 505.730 us; speedup vs baseline: 1.5692x; 1.2255x over previous
//
#include <hip/hip_runtime.h>

// out[e] = segment_sum(M, dest)[src[e]] - M[rev_index[e]]
// E = 800,000, D = 64 (fp32), N_NODES = 50,000.
//
// Round-9: r5 CSR pipeline (best, 497) with the reduce rewritten for MLP:
//  - r5 reduce was the biggest kernel (~130 us, 6 G rows/s) and is dependent-
//    chain limited (order[i] -> M[order[i]], dword loads: whole wave on one
//    row at 4 B/lane). The gather proves the chip does 20 G rows/s on the
//    same random-row pattern with float4 loads.
//  - New reduce: wave=node, lane=(row-slot rs 0..3, quad c4 0..15). Per iter:
//    ONE coalesced order load covers 16 row ids (shfl-distributed), then 4
//    float4 row loads in flight (16 rows/iter, 16 B/lane). Degree-16 node =
//    1 iteration. Cross-slot shfl_xor reduce, float4 Mv write.
// Everything else byte-identical to r5 for attribution.
// Rules: no fp32 global atomics (r3), no hot-line atomics (r4), no fp16/LLC
// tricks (r6 null), no owner-computes (r7/r8: scan-match latency floor).

#define D 64
#define N_NODES 50000

typedef float f4 __attribute__((ext_vector_type(4)));

// K1: histogram of dest, 4 edges/thread via int4.
__global__ void agg_hist(const int* __restrict__ dest, int* __restrict__ counts, int E) {
    int t = blockIdx.x * blockDim.x + threadIdx.x;
    int e = t << 2;
    if (e + 3 < E) {
        int4 d = *reinterpret_cast<const int4*>(dest + e);
        atomicAdd(counts + d.x, 1);
        atomicAdd(counts + d.y, 1);
        atomicAdd(counts + d.z, 1);
        atomicAdd(counts + d.w, 1);
    } else {
        for (; e < E; ++e) atomicAdd(counts + dest[e], 1);
    }
}

// K2: wave-aggregated segment-start allocation (replaces exclusive scan).
__global__ void agg_alloc(const int* __restrict__ counts,
                          int* __restrict__ starts,
                          int* __restrict__ cursor,
                          int* __restrict__ gtotal, int N) {
    int n = blockIdx.x * blockDim.x + threadIdx.x;
    int lane = threadIdx.x & 63;
    int c = (n < N) ? counts[n] : 0;
    int x = c;
    #pragma unroll
    for (int off = 1; off < 64; off <<= 1) {
        int y = __shfl_up(x, off, 64);
        if (lane >= off) x += y;
    }
    int base = 0;
    if (lane == 63) base = atomicAdd(gtotal, x);
    base = __shfl(base, 63, 64);
    int s = base + x - c;
    if (n < N) { starts[n] = s; cursor[n] = s; }
}

// K3: bin edge ids by dest, 4 edges/thread.
__global__ void agg_bin(const int* __restrict__ dest, int* __restrict__ cursor,
                        int* __restrict__ order, int E) {
    int t = blockIdx.x * blockDim.x + threadIdx.x;
    int e = t << 2;
    if (e + 3 < E) {
        int4 d = *reinterpret_cast<const int4*>(dest + e);
        int p0 = atomicAdd(cursor + d.x, 1); order[p0] = e;
        int p1 = atomicAdd(cursor + d.y, 1); order[p1] = e + 1;
        int p2 = atomicAdd(cursor + d.z, 1); order[p2] = e + 2;
        int p3 = atomicAdd(cursor + d.w, 1); order[p3] = e + 3;
    } else {
        for (; e < E; ++e) {
            int pos = atomicAdd(cursor + dest[e], 1);
            order[pos] = e;
        }
    }
}

// K4: wave = node; lane = (rs, c4). 16 rows / iteration, float4 loads.
__global__ void agg_reduce(const float* __restrict__ M,
                           const int* __restrict__ order,
                           const int* __restrict__ starts,
                           const int* __restrict__ counts,
                           float* __restrict__ Mv) {
    int lane = threadIdx.x & 63;
    int node = (blockIdx.x * blockDim.x + threadIdx.x) >> 6;
    if (node >= N_NODES) return;
    int beg = starts[node];
    int cnt = counts[node];
    int c4 = lane & 15;
    int rs = lane >> 4;
    int r0 = rs << 2;
    f4 z = {0.f, 0.f, 0.f, 0.f};
    f4 acc0 = z, acc1 = z, acc2 = z, acc3 = z;
    for (int i = 0; i < cnt; i += 16) {
        int idx = i + c4;
        // one coalesced order load serves 16 rows (lanes 16+ re-read same line)
        int ordv = order[beg + ((idx < cnt) ? idx : cnt - 1)];
        int e0 = __shfl(ordv, r0 + 0, 64);
        int e1 = __shfl(ordv, r0 + 1, 64);
        int e2 = __shfl(ordv, r0 + 2, 64);
        int e3 = __shfl(ordv, r0 + 3, 64);
        // 4 independent float4 row loads in flight per wave
        f4 v0 = reinterpret_cast<const f4*>(M + (size_t)e0 * D)[c4];
        f4 v1 = reinterpret_cast<const f4*>(M + (size_t)e1 * D)[c4];
        f4 v2 = reinterpret_cast<const f4*>(M + (size_t)e2 * D)[c4];
        f4 v3 = reinterpret_cast<const f4*>(M + (size_t)e3 * D)[c4];
        acc0 += (i + r0 + 0 < cnt) ? v0 : z;
        acc1 += (i + r0 + 1 < cnt) ? v1 : z;
        acc2 += (i + r0 + 2 < cnt) ? v2 : z;
        acc3 += (i + r0 + 3 < cnt) ? v3 : z;
    }
    f4 acc = (acc0 + acc1) + (acc2 + acc3);
    #pragma unroll
    for (int off = 16; off < 64; off <<= 1) {   // reduce across the 4 row-slots
        f4 o;
        o.x = __shfl_xor(acc.x, off, 64);
        o.y = __shfl_xor(acc.y, off, 64);
        o.z = __shfl_xor(acc.z, off, 64);
        o.w = __shfl_xor(acc.w, off, 64);
        acc += o;
    }
    if (rs == 0)
        reinterpret_cast<f4*>(Mv + (size_t)node * D)[c4] = acc;  // coalesced
}

// K5: out[e] = Mv[src[e]] - M[rev[e]]. 2 edges per 16-lane group -> 4
// outstanding row loads per thread. nt stores: out is never re-read.
__global__ void agg_gather(const float* __restrict__ Mv,
                           const float* __restrict__ M,
                           const int* __restrict__ src,
                           const int* __restrict__ rev,
                           float* __restrict__ out,
                           int E) {
    int gid = blockIdx.x * blockDim.x + threadIdx.x;
    int p  = gid >> 4;
    int c4 = gid & 15;
    int e0 = p << 1;
    if (e0 >= E) return;
    int e1 = e0 + 1;
    int e1c = (e1 < E) ? e1 : e0;
    int s0 = src[e0], r0 = rev[e0];
    int s1 = src[e1c], r1 = rev[e1c];
    f4 a0 = reinterpret_cast<const f4*>(Mv + (size_t)s0 * D)[c4];
    f4 b0 = reinterpret_cast<const f4*>(M  + (size_t)r0 * D)[c4];
    f4 a1 = reinterpret_cast<const f4*>(Mv + (size_t)s1 * D)[c4];
    f4 b1 = reinterpret_cast<const f4*>(M  + (size_t)r1 * D)[c4];
    f4 o0 = a0 - b0;
    __builtin_nontemporal_store(o0, reinterpret_cast<f4*>(out + (size_t)e0 * D) + c4);
    if (e1 < E) {
        f4 o1 = a1 - b1;
        __builtin_nontemporal_store(o1, reinterpret_cast<f4*>(out + (size_t)e1 * D) + c4);
    }
}

extern "C" void kernel_launch(void* const* d_in, const int* in_sizes, int n_in,
                              void* d_out, int out_size, void* d_ws, size_t ws_size,
                              hipStream_t stream) {
    const float* M   = (const float*)d_in[0];
    const int*   ei  = (const int*)d_in[1];   // (2, E) row-major: [src | dest]
    const int*   rev = (const int*)d_in[2];

    int E = in_sizes[0] / D;                  // 800,000
    const int* src  = ei;
    const int* dest = ei + E;

    // Workspace (~16.3 MB)
    int*   counts = (int*)d_ws;                        // 50,176 ints
    int*   gtotal = counts + 50176;                    // 64 ints (1 used)
    int*   starts = gtotal + 64;                       // 50,176 ints
    int*   cursor = starts + 50176;                    // 50,176 ints
    int*   order  = cursor + 50176;                    // E ints
    float* Mv     = (float*)(order + ((E + 63) & ~63)); // 12.8 MB

    hipMemsetAsync(counts, 0, (50176 + 64) * sizeof(int), stream);

    int hb = ((E + 3) / 4 + 255) / 256;
    agg_hist<<<hb, 256, 0, stream>>>(dest, counts, E);

    int ab = (N_NODES + 255) / 256;
    agg_alloc<<<ab, 256, 0, stream>>>(counts, starts, cursor, gtotal, N_NODES);

    agg_bin<<<hb, 256, 0, stream>>>(dest, cursor, order, E);

    int rb = (N_NODES * 64 + 255) / 256;      // one wave per node
    agg_reduce<<<rb, 256, 0, stream>>>(M, order, starts, counts, Mv);

    int gb = (int)(((size_t)((E + 1) / 2) * 16 + 255) / 256);
    agg_gather<<<gb, 256, 0, stream>>>(Mv, M, src, rev, (float*)d_out, E);
}